// Round 16
// baseline (213.213 us; speedup 1.0000x reference)
//
#include <hip/hip_runtime.h>
#include <stdint.h>
#include <stddef.h>

typedef __attribute__((ext_vector_type(8))) short short8;
typedef __attribute__((ext_vector_type(4))) float f32x4;
typedef __attribute__((ext_vector_type(4))) int i32x4;

#define T_DIM 8192
#define M_DIM 4096
#define K_DIM 4096

// f32 -> bf16 round-to-nearest-even (fallback path only)
__device__ __forceinline__ unsigned short f2b(float f) {
    unsigned int u = __builtin_bit_cast(unsigned int, f);
    u += 0x7fffu + ((u >> 16) & 1u);
    return (unsigned short)(u >> 16);
}

__device__ __forceinline__ void async_copy16(const void* g, const void* l) {
    __builtin_amdgcn_global_load_lds(
        (const __attribute__((address_space(1))) unsigned int*)g,
        (__attribute__((address_space(3))) unsigned int*)l,
        16, 0, 0);
}

// ---------------------------------------------------------------------------
// prep_w (4096 blocks x 512): block = weight row m. Dequant -> qw (f32,
// exact reference path); cw[m] = max_t mv[m,t] via in-block reduce
// (R13-verified); wq = rint(lut*127*mv/cw[m]) (i8, per-column scale).
// Split from the x-path: R11's two-kernel prep measured 63 us vs 73-79 fused.
// ---------------------------------------------------------------------------
__global__ __launch_bounds__(512) void prep_w(const float* __restrict__ w,
                                              const float* __restrict__ maxval,
                                              const float* __restrict__ lut_g,
                                              float* __restrict__ qw,
                                              signed char* __restrict__ wq,
                                              float* __restrict__ cw) {
    __shared__ float wm[8];
    __shared__ float lut[16];
    const int tid = threadIdx.x;
    const int m = blockIdx.x;                       // weight row
    if (tid < 16) lut[tid] = lut_g[tid];

    size_t base = ((size_t)m * 512 + tid) * 8;      // = m*4096 + tid*8
    float mv = maxval[base >> 6];                   // = maxval[m*64 + tid/8]

    // in-block cw[m] = max over the row's 64 scale blocks
    float mx = mv;
    #pragma unroll
    for (int off = 1; off < 64; off <<= 1)
        mx = fmaxf(mx, __shfl_xor(mx, off, 64));
    if ((tid & 63) == 0) wm[tid >> 6] = mx;
    __syncthreads();
    float cwm = fmaxf(fmaxf(fmaxf(wm[0], wm[1]), fmaxf(wm[2], wm[3])),
                      fmaxf(fmaxf(wm[4], wm[5]), fmaxf(wm[6], wm[7])));

    float4 w0 = *reinterpret_cast<const float4*>(w + base);
    float4 w1 = *reinterpret_cast<const float4*>(w + base + 4);
    float vin[8] = {w0.x, w0.y, w0.z, w0.w, w1.x, w1.y, w1.z, w1.w};
    float outv[8];
    int   li[8];

    #pragma unroll
    for (int e = 0; e < 8; ++e) {
        float v = vin[e] / mv;
        float bd = fabsf(v - lut[0]);
        int best = 0;
        #pragma unroll
        for (int k = 1; k < 16; ++k) {
            float d = fabsf(v - lut[k]);
            if (d < bd) { bd = d; best = k; }
        }
        outv[e] = lut[best] * mv;
        li[e]   = best;
    }

    float4 o0; o0.x = outv[0]; o0.y = outv[1]; o0.z = outv[2]; o0.w = outv[3];
    float4 o1; o1.x = outv[4]; o1.y = outv[5]; o1.z = outv[6]; o1.w = outv[7];
    *reinterpret_cast<float4*>(qw + base)     = o0;
    *reinterpret_cast<float4*>(qw + base + 4) = o1;

    if (wq != nullptr) {
        float s = 127.0f * mv / cwm;
        unsigned u0 = 0, u1 = 0;
        #pragma unroll
        for (int e = 0; e < 4; ++e) {
            int q = (int)rintf(lut[li[e]] * s);
            u0 |= ((unsigned)(q & 255)) << (8 * e);
        }
        #pragma unroll
        for (int e = 0; e < 4; ++e) {
            int q = (int)rintf(lut[li[4 + e]] * s);
            u1 |= ((unsigned)(q & 255)) << (8 * e);
        }
        uint2 pk; pk.x = u0; pk.y = u1;
        *reinterpret_cast<uint2*>(wq + base) = pk;
        if (tid == 0) cw[m] = cwm;
    }
}

// ---------------------------------------------------------------------------
// prep_x (8192 blocks x 512): block = x row. Per-row quantize -> xq (i8),
// scale rowmax/127; sx[row] = rowmax/127^2. (R11-verified path.)
// ---------------------------------------------------------------------------
__global__ __launch_bounds__(512) void prep_x(const float* __restrict__ x,
                                              signed char* __restrict__ xq,
                                              float* __restrict__ sx) {
    __shared__ float wm[8];
    const int row = blockIdx.x;
    const int tid = threadIdx.x;
    const float* xr = x + (size_t)row * K_DIM;

    float4 a = *reinterpret_cast<const float4*>(xr + tid * 8);
    float4 b = *reinterpret_cast<const float4*>(xr + tid * 8 + 4);
    float v[8] = {a.x, a.y, a.z, a.w, b.x, b.y, b.z, b.w};

    float mx = 0.0f;
    #pragma unroll
    for (int e = 0; e < 8; ++e) mx = fmaxf(mx, fabsf(v[e]));
    #pragma unroll
    for (int off = 1; off < 64; off <<= 1)
        mx = fmaxf(mx, __shfl_xor(mx, off, 64));
    if ((tid & 63) == 0) wm[tid >> 6] = mx;
    __syncthreads();
    float rmax = fmaxf(fmaxf(fmaxf(wm[0], wm[1]), fmaxf(wm[2], wm[3])),
                       fmaxf(fmaxf(wm[4], wm[5]), fmaxf(wm[6], wm[7])));
    float inv = rmax > 0.0f ? 127.0f / rmax : 0.0f;

    unsigned u0 = 0, u1 = 0;
    #pragma unroll
    for (int e = 0; e < 4; ++e) {
        int q = (int)rintf(v[e] * inv);
        q = q > 127 ? 127 : (q < -127 ? -127 : q);
        u0 |= ((unsigned)(q & 255)) << (8 * e);
    }
    #pragma unroll
    for (int e = 0; e < 4; ++e) {
        int q = (int)rintf(v[4 + e] * inv);
        q = q > 127 ? 127 : (q < -127 ? -127 : q);
        u1 |= ((unsigned)(q & 255)) << (8 * e);
    }
    uint2 pk; pk.x = u0; pk.y = u1;
    *reinterpret_cast<uint2*>(xq + (size_t)row * K_DIM + tid * 8) = pk;

    if (tid == 0) sx[row] = rmax / 16129.0f;   // rowmax / 127^2
}

// ---------------------------------------------------------------------------
// i8 256x256 GEMM, 2 phases per K-tile (R13's exact schedule — best measured
// at 131.5 us steady):
//   acci = Σ xq*wq (pure i32 C-operand accumulation); y = acci*sx[t]*cw[m].
// 8 waves (2Mx4N), BK=64, LDS 64KB dbuf (2 blocks/CU); regions 8KB:
//   r0=A(MH0) r1=B(NH1) r2=A(MH1) r3=B(NH0).
// PH_A(t): reads r0,r1,r3 (8 ds_reads); stage r2 of t+1 (1 copy);
//          barrier; MFMA quads (0,0)+(0,1) (16).
// PH_B(t): reads r2 (4 ds_reads); stage r0,r1,r3 of t+2 (3 copies);
//          vmcnt(3) BEFORE barrier -> retires B(t-1)'s 3 + A(t)'s 1 =
//          all of tile t+1, certified for PH_A(t+1)'s reads;
//          barrier; MFMA quads (1,1)+(1,0) (16).
// Overwrite safety: staged region's last read is exactly one barrier back.
// Fragment mfma_i32_16x16x64_i8: lane k0=(lane>>4)*16 [HW-verified R9/R11].
// LDS swizzle slot=q^((row>>1)&3) [HW-verified: 0 conflicts].
// Schedule-lever history: 4-phase=150us (R11), 2-phase=131.5 (R13),
// 3-buf 1-phase=137 (R14, 1 blk/CU), pipelined reads=136 (R15) — R13 wins.
// ---------------------------------------------------------------------------

#define RD_A8(BUF, MH)                                                        \
  { _Pragma("unroll") for (int mi = 0; mi < 4; ++mi) {                        \
        int r_ = wr * 64 + mi * 16 + fr;                                      \
        aI[mi] = *reinterpret_cast<const i32x4*>(                             \
            lds + (BUF) * 32768 + (MH) * 16384 + r_ * 64 +                    \
            (fkB ^ (((r_ >> 1) & 3) << 4)));                                  \
  } }

#define RD_B8(BUF, NH, DST)                                                   \
  { _Pragma("unroll") for (int ni = 0; ni < 2; ++ni) {                        \
        int r_ = wc * 32 + ni * 16 + fr;                                      \
        DST[ni] = *reinterpret_cast<const i32x4*>(                            \
            lds + (BUF) * 32768 + ((NH) ? 8192 : 24576) + r_ * 64 +           \
            (fkB ^ (((r_ >> 1) & 3) << 4)));                                  \
  } }

#define MFMA_Q(MH, NH, B)                                                     \
    _Pragma("unroll") for (int mi = 0; mi < 4; ++mi)                          \
    _Pragma("unroll") for (int ni = 0; ni < 2; ++ni)                          \
        acci[(MH) * 4 + mi][(NH) * 2 + ni] =                                  \
            __builtin_amdgcn_mfma_i32_16x16x64_i8(                            \
                aI[mi], B[ni],                                                \
                acci[(MH) * 4 + mi][(NH) * 2 + ni], 0, 0, 0);

#define PH_A(BUF, TNXT)                                                       \
  { RD_A8(BUF, 0)                                                             \
    RD_B8(BUF, 0, bI0)                                                        \
    RD_B8(BUF, 1, bI1)                                                        \
    stage_r2(TNXT);                                                           \
    asm volatile("" ::: "memory");                                            \
    __builtin_amdgcn_s_barrier();                                             \
    asm volatile("" ::: "memory");                                            \
    __builtin_amdgcn_s_setprio(1);                                            \
    MFMA_Q(0, 0, bI0)                                                         \
    MFMA_Q(0, 1, bI1)                                                         \
    __builtin_amdgcn_s_setprio(0); }

#define PH_B(BUF, TNXT2)                                                      \
  { RD_A8(BUF, 1)                                                             \
    stage_r013(TNXT2);                                                        \
    asm volatile("s_waitcnt vmcnt(3)" ::: "memory");                          \
    __builtin_amdgcn_s_barrier();                                             \
    asm volatile("" ::: "memory");                                            \
    __builtin_amdgcn_s_setprio(1);                                            \
    MFMA_Q(1, 1, bI1)                                                         \
    MFMA_Q(1, 0, bI0)                                                         \
    __builtin_amdgcn_s_setprio(0); }

__global__ __launch_bounds__(512, 2) void gemm_i8(
    const signed char* __restrict__ Aq,   // [T][K] int8
    const signed char* __restrict__ Bq,   // [M][K] int8
    const float* __restrict__ sxp,        // [T] rowmax/127^2
    const float* __restrict__ cwp,        // [M] per-column w scale
    float* __restrict__ Y) {
    __shared__ __align__(16) unsigned char lds[65536];

    const int tid  = threadIdx.x;
    const int lane = tid & 63;
    const int wid  = tid >> 6;
    const int wr   = wid >> 2;
    const int wc   = wid & 3;

    const int bid  = blockIdx.x;
    const int swz  = (bid & 7) * 64 + (bid >> 3);   // bijective XCD swizzle
    const int brow = swz >> 4;
    const int bcol = swz & 15;
    const int row0 = brow * 256;
    const int col0 = bcol * 256;

    const int fr  = lane & 15;
    const int fkB = (lane >> 4) * 16;

    i32x4 acci[8][4] = {};
    i32x4 aI[4], bI0[2], bI1[2];

    const int srow  = wid * 16 + (lane >> 2);                 // staging row 0..127
    const int sslot = ((lane & 3) ^ ((srow >> 1) & 3)) * 16;  // pre-swizzled src
    const unsigned sdst = wid * 1024u;                        // linear LDS dest

    auto stage_r013 = [&](int t) {
        int tc  = t < 64 ? t : 63;
        unsigned boff = (unsigned)(t & 1) * 32768u;
        {   // r0: A rows (r%128)<64
            const char* g = (const char*)Aq +
                (size_t)(row0 + ((srow >> 6) << 7) + (srow & 63)) * K_DIM + tc * 64 + sslot;
            async_copy16(g, lds + boff + sdst); }
        {   // r1: B rows (r%64)>=32
            const char* g = (const char*)Bq +
                (size_t)(col0 + ((srow >> 5) << 6) + 32 + (srow & 31)) * K_DIM + tc * 64 + sslot;
            async_copy16(g, lds + boff + 8192u + sdst); }
        {   // r3: B rows (r%64)<32
            const char* g = (const char*)Bq +
                (size_t)(col0 + ((srow >> 5) << 6) + (srow & 31)) * K_DIM + tc * 64 + sslot;
            async_copy16(g, lds + boff + 24576u + sdst); }
    };
    auto stage_r2 = [&](int t) {
        int tc  = t < 64 ? t : 63;
        unsigned boff = (unsigned)(t & 1) * 32768u;
        const char* g = (const char*)Aq +
            (size_t)(row0 + 64 + ((srow >> 6) << 7) + (srow & 63)) * K_DIM + tc * 64 + sslot;
        async_copy16(g, lds + boff + 16384u + sdst);
    };

    // prologue: t0 r0,r1,r3 + t0 r2 + t1 r0,r1,r3 (7 copies);
    // vmcnt(3) retires tile0's 4 -> certified; barrier.
    stage_r013(0);
    stage_r2(0);
    stage_r013(1);
    asm volatile("s_waitcnt vmcnt(3)" ::: "memory");
    __builtin_amdgcn_s_barrier();
    asm volatile("" ::: "memory");

    // main loop: 32 iter x 2 K-tiles x 2 phases
    for (int i = 0; i < 32; ++i) {
        PH_A(0, 2 * i + 1)   // stage r2(t1)
        PH_B(0, 2 * i + 2)   // stage r013(t2); vmcnt(3) certifies tile t1
        PH_A(1, 2 * i + 2)   // stage r2(t2)
        PH_B(1, 2 * i + 3)   // stage r013(t3); vmcnt(3) certifies tile t2
    }
    asm volatile("s_waitcnt vmcnt(0)" ::: "memory");

    // epilogue: C/D col=lane&15, row=(lane>>4)*4+reg; y = acci*sx[t]*cw[m]
    const int rb = (lane >> 4) * 4;
    float cwv[4];
    #pragma unroll
    for (int n = 0; n < 4; ++n) cwv[n] = cwp[col0 + wc * 64 + n * 16 + fr];
    #pragma unroll
    for (int m = 0; m < 8; ++m) {
        const int t0 = row0 + wr * 128 + m * 16 + rb;
        f32x4 sx4 = *reinterpret_cast<const f32x4*>(sxp + t0);
        #pragma unroll
        for (int n = 0; n < 4; ++n)
            #pragma unroll
            for (int r = 0; r < 4; ++r)
                Y[(size_t)(t0 + r) * M_DIM + col0 + wc * 64 + n * 16 + fr] =
                    (float)acci[m][n][r] * sx4[r] * cwv[n];
    }
}

// ---------------------------------------------------------------------------
// Fallback m97-style f32->bf16-in-reg GEMM (only if ws too small)
// ---------------------------------------------------------------------------
__global__ __launch_bounds__(256) void gemm_fb(const float* __restrict__ Ap,
                                               const float* __restrict__ Bp,
                                               float* __restrict__ Y) {
    constexpr int BK = 64;
    __shared__ unsigned short lA[128 * BK];
    __shared__ unsigned short lB[128 * BK];

    const int tid  = threadIdx.x;
    const int lane = tid & 63;
    const int wid  = tid >> 6;
    const int wr   = wid >> 1;
    const int wc   = wid & 1;
    const int brow = blockIdx.x >> 5;
    const int bcol = blockIdx.x & 31;
    const int row0 = brow * 128;
    const int col0 = bcol * 128;

    f32x4 acc[4][4] = {};
    const int fr = lane & 15;
    const int fk = (lane >> 4) * 8;
    const int srow = lane >> 3;
    const int scol = (lane & 7) * 8;

    for (int k0 = 0; k0 < K_DIM; k0 += BK) {
        #pragma unroll
        for (int i = 0; i < 4; ++i) {
            const int c = wid * 4 + i;
            const int r = c * 8 + srow;
            const float* g = Ap + (size_t)(row0 + r) * K_DIM + k0 + scol;
            float4 v0 = *reinterpret_cast<const float4*>(g);
            float4 v1 = *reinterpret_cast<const float4*>(g + 4);
            short8 pk;
            pk[0] = (short)f2b(v0.x); pk[1] = (short)f2b(v0.y);
            pk[2] = (short)f2b(v0.z); pk[3] = (short)f2b(v0.w);
            pk[4] = (short)f2b(v1.x); pk[5] = (short)f2b(v1.y);
            pk[6] = (short)f2b(v1.z); pk[7] = (short)f2b(v1.w);
            *reinterpret_cast<short8*>(lA + c * 512 + lane * 8) = pk;
        }
        #pragma unroll
        for (int i = 0; i < 4; ++i) {
            const int c = wid * 4 + i;
            const int r = c * 8 + srow;
            const float* g = Bp + (size_t)(col0 + r) * K_DIM + k0 + scol;
            float4 v0 = *reinterpret_cast<const float4*>(g);
            float4 v1 = *reinterpret_cast<const float4*>(g + 4);
            short8 pk;
            pk[0] = (short)f2b(v0.x); pk[1] = (short)f2b(v0.y);
            pk[2] = (short)f2b(v0.z); pk[3] = (short)f2b(v0.w);
            pk[4] = (short)f2b(v1.x); pk[5] = (short)f2b(v1.y);
            pk[6] = (short)f2b(v1.z); pk[7] = (short)f2b(v1.w);
            *reinterpret_cast<short8*>(lB + c * 512 + lane * 8) = pk;
        }
        __syncthreads();
        #pragma unroll
        for (int kk = 0; kk < BK; kk += 32) {
            short8 af[4], bfr[4];
            #pragma unroll
            for (int m = 0; m < 4; ++m)
                af[m] = *reinterpret_cast<const short8*>(
                    lA + (wr * 64 + m * 16 + fr) * BK + kk + fk);
            #pragma unroll
            for (int n = 0; n < 4; ++n)
                bfr[n] = *reinterpret_cast<const short8*>(
                    lB + (wc * 64 + n * 16 + fr) * BK + kk + fk);
            #pragma unroll
            for (int m = 0; m < 4; ++m)
                #pragma unroll
                for (int n = 0; n < 4; ++n)
                    acc[m][n] = __builtin_amdgcn_mfma_f32_16x16x32_bf16(
                        af[m], bfr[n], acc[m][n], 0, 0, 0);
        }
        __syncthreads();
    }

    const int orow  = row0 + wr * 64;
    const int ocol  = col0 + wc * 64 + fr;
    const int rbase = (lane >> 4) * 4;
    #pragma unroll
    for (int m = 0; m < 4; ++m)
        #pragma unroll
        for (int n = 0; n < 4; ++n)
            #pragma unroll
            for (int r = 0; r < 4; ++r)
                Y[(size_t)(orow + m * 16 + rbase + r) * M_DIM + ocol + n * 16] =
                    acc[m][n][r];
}

// ---------------------------------------------------------------------------
extern "C" void kernel_launch(void* const* d_in, const int* in_sizes, int n_in,
                              void* d_out, int out_size, void* d_ws, size_t ws_size,
                              hipStream_t stream) {
    const float* x   = (const float*)d_in[0];
    const float* w   = (const float*)d_in[1];
    const float* mv  = (const float*)d_in[2];
    const float* lut = (const float*)d_in[3];

    float* y  = (float*)d_out;
    float* qw = y + (size_t)T_DIM * M_DIM;

    const bool full = ws_size >= (49u << 20);   // need ~48.08 MB

    signed char* xq  = (signed char*)d_ws;                 // 32 MB
    signed char* wqp = xq + (32u << 20);                   // 16 MB
    float*       sx  = (float*)(xq + (48u << 20));         // 32 KB
    float*       cw  = (float*)(xq + (48u << 20) + 65536); // 16 KB

    if (full) {
        prep_w<<<dim3(4096), dim3(512), 0, stream>>>(w, mv, lut, qw, wqp, cw);
        prep_x<<<dim3(8192), dim3(512), 0, stream>>>(x, xq, sx);
        gemm_i8<<<dim3(512), dim3(512), 0, stream>>>(xq, wqp, sx, cw, y);
    } else {
        prep_w<<<dim3(4096), dim3(512), 0, stream>>>(w, mv, lut, qw, nullptr, nullptr);
        dim3 grid((T_DIM / 128) * (M_DIM / 128));
        gemm_fb<<<grid, dim3(256), 0, stream>>>(x, qw, y);
    }
}

// Round 17
// 209.251 us; speedup vs baseline: 1.0189x; 1.0189x over previous
//
#include <hip/hip_runtime.h>
#include <stdint.h>
#include <stddef.h>

typedef __attribute__((ext_vector_type(8))) short short8;
typedef __attribute__((ext_vector_type(4))) float f32x4;
typedef __attribute__((ext_vector_type(4))) int i32x4;

#define T_DIM 8192
#define M_DIM 4096
#define K_DIM 4096

// f32 -> bf16 round-to-nearest-even (fallback path only)
__device__ __forceinline__ unsigned short f2b(float f) {
    unsigned int u = __builtin_bit_cast(unsigned int, f);
    u += 0x7fffu + ((u >> 16) & 1u);
    return (unsigned short)(u >> 16);
}

__device__ __forceinline__ void async_copy16(const void* g, const void* l) {
    __builtin_amdgcn_global_load_lds(
        (const __attribute__((address_space(1))) unsigned int*)g,
        (__attribute__((address_space(3))) unsigned int*)l,
        16, 0, 0);
}

// ---------------------------------------------------------------------------
// prep_all (512 thr) — single fused launch (R13's exact version, best total):
//   blocks [0,4096):  block = weight row m. Dequant -> qw (f32, exact) and
//                     cw[m] = max_t mv[m,t] via in-block reduce; wq i8.
//   blocks [4096,12288): x row quantize -> xq (i8), sx[row] = rowmax/127^2.
// ---------------------------------------------------------------------------
__global__ __launch_bounds__(512) void prep_all(const float* __restrict__ w,
                                                const float* __restrict__ maxval,
                                                const float* __restrict__ lut_g,
                                                float* __restrict__ qw,
                                                signed char* __restrict__ wq,
                                                float* __restrict__ cw,
                                                const float* __restrict__ x,
                                                signed char* __restrict__ xq,
                                                float* __restrict__ sx) {
    __shared__ float wm[8];
    __shared__ float lut[16];
    const int tid = threadIdx.x;

    if (blockIdx.x < 4096) {
        const int m = blockIdx.x;                       // weight row
        if (tid < 16) lut[tid] = lut_g[tid];

        size_t base = ((size_t)m * 512 + tid) * 8;      // = m*4096 + tid*8
        float mv = maxval[base >> 6];                   // = maxval[m*64 + tid/8]

        // in-block cw[m] = max over the row's 64 scale blocks
        float mx = mv;
        #pragma unroll
        for (int off = 1; off < 64; off <<= 1)
            mx = fmaxf(mx, __shfl_xor(mx, off, 64));
        if ((tid & 63) == 0) wm[tid >> 6] = mx;
        __syncthreads();
        float cwm = fmaxf(fmaxf(fmaxf(wm[0], wm[1]), fmaxf(wm[2], wm[3])),
                          fmaxf(fmaxf(wm[4], wm[5]), fmaxf(wm[6], wm[7])));

        float4 w0 = *reinterpret_cast<const float4*>(w + base);
        float4 w1 = *reinterpret_cast<const float4*>(w + base + 4);
        float vin[8] = {w0.x, w0.y, w0.z, w0.w, w1.x, w1.y, w1.z, w1.w};
        float outv[8];
        int   li[8];

        #pragma unroll
        for (int e = 0; e < 8; ++e) {
            float v = vin[e] / mv;
            float bd = fabsf(v - lut[0]);
            int best = 0;
            #pragma unroll
            for (int k = 1; k < 16; ++k) {
                float d = fabsf(v - lut[k]);
                if (d < bd) { bd = d; best = k; }
            }
            outv[e] = lut[best] * mv;
            li[e]   = best;
        }

        float4 o0; o0.x = outv[0]; o0.y = outv[1]; o0.z = outv[2]; o0.w = outv[3];
        float4 o1; o1.x = outv[4]; o1.y = outv[5]; o1.z = outv[6]; o1.w = outv[7];
        *reinterpret_cast<float4*>(qw + base)     = o0;
        *reinterpret_cast<float4*>(qw + base + 4) = o1;

        if (wq != nullptr) {
            float s = 127.0f * mv / cwm;
            unsigned u0 = 0, u1 = 0;
            #pragma unroll
            for (int e = 0; e < 4; ++e) {
                int q = (int)rintf(lut[li[e]] * s);
                u0 |= ((unsigned)(q & 255)) << (8 * e);
            }
            #pragma unroll
            for (int e = 0; e < 4; ++e) {
                int q = (int)rintf(lut[li[4 + e]] * s);
                u1 |= ((unsigned)(q & 255)) << (8 * e);
            }
            uint2 pk; pk.x = u0; pk.y = u1;
            *reinterpret_cast<uint2*>(wq + base) = pk;
            if (tid == 0) cw[m] = cwm;
        }
    } else {
        if (xq == nullptr) return;
        const int row = blockIdx.x - 4096;
        const float* xr = x + (size_t)row * K_DIM;

        float4 a = *reinterpret_cast<const float4*>(xr + tid * 8);
        float4 b = *reinterpret_cast<const float4*>(xr + tid * 8 + 4);
        float v[8] = {a.x, a.y, a.z, a.w, b.x, b.y, b.z, b.w};

        float mx = 0.0f;
        #pragma unroll
        for (int e = 0; e < 8; ++e) mx = fmaxf(mx, fabsf(v[e]));
        #pragma unroll
        for (int off = 1; off < 64; off <<= 1)
            mx = fmaxf(mx, __shfl_xor(mx, off, 64));
        if ((tid & 63) == 0) wm[tid >> 6] = mx;
        __syncthreads();
        float rmax = fmaxf(fmaxf(fmaxf(wm[0], wm[1]), fmaxf(wm[2], wm[3])),
                           fmaxf(fmaxf(wm[4], wm[5]), fmaxf(wm[6], wm[7])));
        float inv = rmax > 0.0f ? 127.0f / rmax : 0.0f;

        unsigned u0 = 0, u1 = 0;
        #pragma unroll
        for (int e = 0; e < 4; ++e) {
            int q = (int)rintf(v[e] * inv);
            q = q > 127 ? 127 : (q < -127 ? -127 : q);
            u0 |= ((unsigned)(q & 255)) << (8 * e);
        }
        #pragma unroll
        for (int e = 0; e < 4; ++e) {
            int q = (int)rintf(v[4 + e] * inv);
            q = q > 127 ? 127 : (q < -127 ? -127 : q);
            u1 |= ((unsigned)(q & 255)) << (8 * e);
        }
        uint2 pk; pk.x = u0; pk.y = u1;
        *reinterpret_cast<uint2*>(xq + (size_t)row * K_DIM + tid * 8) = pk;

        if (tid == 0) sx[row] = rmax / 16129.0f;
    }
}

// ---------------------------------------------------------------------------
// i8 256x256 GEMM, 2 phases/K-tile, pipelined reads (R15 dataflow, verified
// bit-exact) + T19 sched_group_barrier MFMA:ds_read interleave.
// Regime justification (rule #23): per-CU per tile MFMA=1306cy, LDS=~1535cy
// (reads 96KB@85B/cy + staging writes) — co-critical, each ~50% duty
// (measured MfmaUtil 47%). Lockstep barriers make LDS-burst then MFMA-burst;
// SGB pins {MFMA 3, DS_READ 1} / {MFMA 2, DS_READ 1} so each wave feeds both
// pipes concurrently. Reads in-region have NO dependent MFMA in-region
// (consumed next cluster) -> interleave costs nothing on the dep chain.
//   PH_A(t): stage r2(t+1); barrier; [read aI1(t) ∥ MFMA quads (0,0)(0,1)]
//   PH_B(t): stage r013(t+2); vmcnt(3) BEFORE barrier (certifies tile t+1,
//            R11 discipline); barrier; [read t+1 frags ∥ MFMA (1,1)(1,0)]
// B fragments ping-pong (a/b sets); per-acc MFMA order identical to R13 ->
// y bit-identical (absmax must be exactly 0.09765625; deviation = race).
// mfma_i32_16x16x64_i8 lane k0=(lane>>4)*16 [HW-verified R9/R11];
// LDS swizzle slot=q^((row>>1)&3) [HW-verified: 0 conflicts].
// ---------------------------------------------------------------------------

#define SGB_MFMA(N) __builtin_amdgcn_sched_group_barrier(0x008, (N), 0)
#define SGB_DSR(N)  __builtin_amdgcn_sched_group_barrier(0x100, (N), 0)

#define RD_A8(BOFS, MH, DST)                                                  \
  { _Pragma("unroll") for (int mi = 0; mi < 4; ++mi) {                        \
        int r_ = wr * 64 + mi * 16 + fr;                                      \
        DST[mi] = *reinterpret_cast<const i32x4*>(                            \
            lds + (BOFS) + (MH) * 16384 + r_ * 64 +                           \
            (fkB ^ (((r_ >> 1) & 3) << 4)));                                  \
  } }

#define RD_B8(BOFS, NH, DST)                                                  \
  { _Pragma("unroll") for (int ni = 0; ni < 2; ++ni) {                        \
        int r_ = wc * 32 + ni * 16 + fr;                                      \
        DST[ni] = *reinterpret_cast<const i32x4*>(                            \
            lds + (BOFS) + ((NH) ? 8192 : 24576) + r_ * 64 +                  \
            (fkB ^ (((r_ >> 1) & 3) << 4)));                                  \
  } }

#define MFMA_Q(MH, NH, A, B)                                                  \
    _Pragma("unroll") for (int mi = 0; mi < 4; ++mi)                          \
    _Pragma("unroll") for (int ni = 0; ni < 2; ++ni)                          \
        acci[(MH) * 4 + mi][(NH) * 2 + ni] =                                  \
            __builtin_amdgcn_mfma_i32_16x16x64_i8(                            \
                A[mi], B[ni],                                                 \
                acci[(MH) * 4 + mi][(NH) * 2 + ni], 0, 0, 0);

// PH_A(t): stage r2(t+1); barrier; interleave {read aI1(t)} into 16 MFMA
#define PH_A(CBOFS, TNXT, B0C, B1C)                                           \
  { stage_r2(TNXT);                                                           \
    asm volatile("" ::: "memory");                                            \
    __builtin_amdgcn_s_barrier();                                             \
    asm volatile("" ::: "memory");                                            \
    RD_A8(CBOFS, 1, aI1)                                                      \
    __builtin_amdgcn_s_setprio(1);                                            \
    MFMA_Q(0, 0, aI0, B0C)                                                    \
    MFMA_Q(0, 1, aI0, B1C)                                                    \
    SGB_MFMA(3); SGB_DSR(1);                                                  \
    SGB_MFMA(3); SGB_DSR(1);                                                  \
    SGB_MFMA(3); SGB_DSR(1);                                                  \
    SGB_MFMA(3); SGB_DSR(1);                                                  \
    SGB_MFMA(4);                                                              \
    __builtin_amdgcn_s_setprio(0); }

// PH_B(t): stage r013(t+2); vmcnt(3); barrier; interleave {8 reads of t+1}
// into 16 MFMA
#define PH_B(NBOFS, TNXT2, B0C, B1C, B0N, B1N)                                \
  { stage_r013(TNXT2);                                                        \
    asm volatile("s_waitcnt vmcnt(3)" ::: "memory");                          \
    __builtin_amdgcn_s_barrier();                                             \
    asm volatile("" ::: "memory");                                            \
    RD_B8(NBOFS, 0, B0N)                                                      \
    RD_B8(NBOFS, 1, B1N)                                                      \
    RD_A8(NBOFS, 0, aI0)                                                      \
    __builtin_amdgcn_s_setprio(1);                                            \
    MFMA_Q(1, 1, aI1, B1C)                                                    \
    MFMA_Q(1, 0, aI1, B0C)                                                    \
    SGB_MFMA(2); SGB_DSR(1);                                                  \
    SGB_MFMA(2); SGB_DSR(1);                                                  \
    SGB_MFMA(2); SGB_DSR(1);                                                  \
    SGB_MFMA(2); SGB_DSR(1);                                                  \
    SGB_MFMA(2); SGB_DSR(1);                                                  \
    SGB_MFMA(2); SGB_DSR(1);                                                  \
    SGB_MFMA(2); SGB_DSR(1);                                                  \
    SGB_MFMA(2); SGB_DSR(1);                                                  \
    __builtin_amdgcn_s_setprio(0); }

__global__ __launch_bounds__(512, 2) void gemm_i8(
    const signed char* __restrict__ Aq,   // [T][K] int8
    const signed char* __restrict__ Bq,   // [M][K] int8
    const float* __restrict__ sxp,        // [T] rowmax/127^2
    const float* __restrict__ cwp,        // [M] per-column w scale
    float* __restrict__ Y) {
    __shared__ __align__(16) unsigned char lds[65536];

    const int tid  = threadIdx.x;
    const int lane = tid & 63;
    const int wid  = tid >> 6;
    const int wr   = wid >> 2;
    const int wc   = wid & 3;

    const int bid  = blockIdx.x;
    const int swz  = (bid & 7) * 64 + (bid >> 3);   // bijective XCD swizzle
    const int brow = swz >> 4;
    const int bcol = swz & 15;
    const int row0 = brow * 256;
    const int col0 = bcol * 256;

    const int fr  = lane & 15;
    const int fkB = (lane >> 4) * 16;

    i32x4 acci[8][4] = {};
    i32x4 aI0[4], aI1[4];
    i32x4 bI0a[2], bI1a[2], bI0b[2], bI1b[2];

    const int srow  = wid * 16 + (lane >> 2);                 // staging row 0..127
    const int sslot = ((lane & 3) ^ ((srow >> 1) & 3)) * 16;  // pre-swizzled src
    const unsigned sdst = wid * 1024u;                        // linear LDS dest

    auto stage_r013 = [&](int t) {
        int tc  = t < 64 ? t : 63;
        unsigned boff = (unsigned)(t & 1) * 32768u;
        {   // r0: A rows (r%128)<64
            const char* g = (const char*)Aq +
                (size_t)(row0 + ((srow >> 6) << 7) + (srow & 63)) * K_DIM + tc * 64 + sslot;
            async_copy16(g, lds + boff + sdst); }
        {   // r1: B rows (r%64)>=32
            const char* g = (const char*)Bq +
                (size_t)(col0 + ((srow >> 5) << 6) + 32 + (srow & 31)) * K_DIM + tc * 64 + sslot;
            async_copy16(g, lds + boff + 8192u + sdst); }
        {   // r3: B rows (r%64)<32
            const char* g = (const char*)Bq +
                (size_t)(col0 + ((srow >> 5) << 6) + (srow & 31)) * K_DIM + tc * 64 + sslot;
            async_copy16(g, lds + boff + 24576u + sdst); }
    };
    auto stage_r2 = [&](int t) {
        int tc  = t < 64 ? t : 63;
        unsigned boff = (unsigned)(t & 1) * 32768u;
        const char* g = (const char*)Aq +
            (size_t)(row0 + 64 + ((srow >> 6) << 7) + (srow & 63)) * K_DIM + tc * 64 + sslot;
        async_copy16(g, lds + boff + 16384u + sdst);
    };

    // prologue: t0 r013 + t0 r2 + t1 r013 (7 copies); vmcnt(3) retires
    // tile0's 4 -> certified; barrier; pre-read tile0 fragments for MFMA_A(0).
    stage_r013(0);
    stage_r2(0);
    stage_r013(1);
    asm volatile("s_waitcnt vmcnt(3)" ::: "memory");
    __builtin_amdgcn_s_barrier();
    asm volatile("" ::: "memory");
    RD_B8(0u, 0, bI0a)
    RD_B8(0u, 1, bI1a)
    RD_A8(0u, 0, aI0)

    // main loop: 32 iter x 2 K-tiles x 2 phases (B-sets ping-pong a/b)
    for (int i = 0; i < 32; ++i) {
        PH_A(0u,      2 * i + 1, bI0a, bI1a)                     // tile 2i
        PH_B(32768u,  2 * i + 2, bI0a, bI1a, bI0b, bI1b)         // reads t+1
        PH_A(32768u,  2 * i + 2, bI0b, bI1b)                     // tile 2i+1
        PH_B(0u,      2 * i + 3, bI0b, bI1b, bI0a, bI1a)         // reads t+2
    }
    asm volatile("s_waitcnt vmcnt(0)" ::: "memory");

    // epilogue: C/D col=lane&15, row=(lane>>4)*4+reg; y = acci*sx[t]*cw[m]
    const int rb = (lane >> 4) * 4;
    float cwv[4];
    #pragma unroll
    for (int n = 0; n < 4; ++n) cwv[n] = cwp[col0 + wc * 64 + n * 16 + fr];
    #pragma unroll
    for (int m = 0; m < 8; ++m) {
        const int t0 = row0 + wr * 128 + m * 16 + rb;
        f32x4 sx4 = *reinterpret_cast<const f32x4*>(sxp + t0);
        #pragma unroll
        for (int n = 0; n < 4; ++n)
            #pragma unroll
            for (int r = 0; r < 4; ++r)
                Y[(size_t)(t0 + r) * M_DIM + col0 + wc * 64 + n * 16 + fr] =
                    (float)acci[m][n][r] * sx4[r] * cwv[n];
    }
}

// ---------------------------------------------------------------------------
// Fallback m97-style f32->bf16-in-reg GEMM (only if ws too small)
// ---------------------------------------------------------------------------
__global__ __launch_bounds__(256) void gemm_fb(const float* __restrict__ Ap,
                                               const float* __restrict__ Bp,
                                               float* __restrict__ Y) {
    constexpr int BK = 64;
    __shared__ unsigned short lA[128 * BK];
    __shared__ unsigned short lB[128 * BK];

    const int tid  = threadIdx.x;
    const int lane = tid & 63;
    const int wid  = tid >> 6;
    const int wr   = wid >> 1;
    const int wc   = wid & 1;
    const int brow = blockIdx.x >> 5;
    const int bcol = blockIdx.x & 31;
    const int row0 = brow * 128;
    const int col0 = bcol * 128;

    f32x4 acc[4][4] = {};
    const int fr = lane & 15;
    const int fk = (lane >> 4) * 8;
    const int srow = lane >> 3;
    const int scol = (lane & 7) * 8;

    for (int k0 = 0; k0 < K_DIM; k0 += BK) {
        #pragma unroll
        for (int i = 0; i < 4; ++i) {
            const int c = wid * 4 + i;
            const int r = c * 8 + srow;
            const float* g = Ap + (size_t)(row0 + r) * K_DIM + k0 + scol;
            float4 v0 = *reinterpret_cast<const float4*>(g);
            float4 v1 = *reinterpret_cast<const float4*>(g + 4);
            short8 pk;
            pk[0] = (short)f2b(v0.x); pk[1] = (short)f2b(v0.y);
            pk[2] = (short)f2b(v0.z); pk[3] = (short)f2b(v0.w);
            pk[4] = (short)f2b(v1.x); pk[5] = (short)f2b(v1.y);
            pk[6] = (short)f2b(v1.z); pk[7] = (short)f2b(v1.w);
            *reinterpret_cast<short8*>(lA + c * 512 + lane * 8) = pk;
        }
        #pragma unroll
        for (int i = 0; i < 4; ++i) {
            const int c = wid * 4 + i;
            const int r = c * 8 + srow;
            const float* g = Bp + (size_t)(col0 + r) * K_DIM + k0 + scol;
            float4 v0 = *reinterpret_cast<const float4*>(g);
            float4 v1 = *reinterpret_cast<const float4*>(g + 4);
            short8 pk;
            pk[0] = (short)f2b(v0.x); pk[1] = (short)f2b(v0.y);
            pk[2] = (short)f2b(v0.z); pk[3] = (short)f2b(v0.w);
            pk[4] = (short)f2b(v1.x); pk[5] = (short)f2b(v1.y);
            pk[6] = (short)f2b(v1.z); pk[7] = (short)f2b(v1.w);
            *reinterpret_cast<short8*>(lB + c * 512 + lane * 8) = pk;
        }
        __syncthreads();
        #pragma unroll
        for (int kk = 0; kk < BK; kk += 32) {
            short8 af[4], bfr[4];
            #pragma unroll
            for (int m = 0; m < 4; ++m)
                af[m] = *reinterpret_cast<const short8*>(
                    lA + (wr * 64 + m * 16 + fr) * BK + kk + fk);
            #pragma unroll
            for (int n = 0; n < 4; ++n)
                bfr[n] = *reinterpret_cast<const short8*>(
                    lB + (wc * 64 + n * 16 + fr) * BK + kk + fk);
            #pragma unroll
            for (int m = 0; m < 4; ++m)
                #pragma unroll
                for (int n = 0; n < 4; ++n)
                    acc[m][n] = __builtin_amdgcn_mfma_f32_16x16x32_bf16(
                        af[m], bfr[n], acc[m][n], 0, 0, 0);
        }
        __syncthreads();
    }

    const int orow  = row0 + wr * 64;
    const int ocol  = col0 + wc * 64 + fr;
    const int rbase = (lane >> 4) * 4;
    #pragma unroll
    for (int m = 0; m < 4; ++m)
        #pragma unroll
        for (int n = 0; n < 4; ++n)
            #pragma unroll
            for (int r = 0; r < 4; ++r)
                Y[(size_t)(orow + m * 16 + rbase + r) * M_DIM + ocol + n * 16] =
                    acc[m][n][r];
}

// ---------------------------------------------------------------------------
extern "C" void kernel_launch(void* const* d_in, const int* in_sizes, int n_in,
                              void* d_out, int out_size, void* d_ws, size_t ws_size,
                              hipStream_t stream) {
    const float* x   = (const float*)d_in[0];
    const float* w   = (const float*)d_in[1];
    const float* mv  = (const float*)d_in[2];
    const float* lut = (const float*)d_in[3];

    float* y  = (float*)d_out;
    float* qw = y + (size_t)T_DIM * M_DIM;

    const bool full = ws_size >= (49u << 20);   // need ~48.08 MB

    signed char* xq  = (signed char*)d_ws;                 // 32 MB
    signed char* wqp = xq + (32u << 20);                   // 16 MB
    float*       sx  = (float*)(xq + (48u << 20));         // 32 KB
    float*       cw  = (float*)(xq + (48u << 20) + 65536); // 16 KB

    if (full) {
        prep_all<<<dim3(12288), dim3(512), 0, stream>>>(
            w, mv, lut, qw, wqp, cw, x, xq, sx);
        gemm_i8<<<dim3(512), dim3(512), 0, stream>>>(xq, wqp, sx, cw, y);
    } else {
        prep_all<<<dim3(4096), dim3(512), 0, stream>>>(
            w, mv, lut, qw, nullptr, nullptr, x, nullptr, nullptr);
        dim3 grid((T_DIM / 128) * (M_DIM / 128));
        gemm_fb<<<grid, dim3(256), 0, stream>>>(x, qw, y);
    }
}

// Round 19
// 202.716 us; speedup vs baseline: 1.0518x; 1.0322x over previous
//
#include <hip/hip_runtime.h>
#include <stdint.h>
#include <stddef.h>

typedef __attribute__((ext_vector_type(8))) short short8;
typedef __attribute__((ext_vector_type(4))) float f32x4;
typedef __attribute__((ext_vector_type(4))) int i32x4;

#define T_DIM 8192
#define M_DIM 4096
#define K_DIM 4096

// f32 -> bf16 round-to-nearest-even (fallback path only)
__device__ __forceinline__ unsigned short f2b(float f) {
    unsigned int u = __builtin_bit_cast(unsigned int, f);
    u += 0x7fffu + ((u >> 16) & 1u);
    return (unsigned short)(u >> 16);
}

__device__ __forceinline__ void async_copy16(const void* g, const void* l) {
    __builtin_amdgcn_global_load_lds(
        (const __attribute__((address_space(1))) unsigned int*)g,
        (__attribute__((address_space(3))) unsigned int*)l,
        16, 0, 0);
}

// ---------------------------------------------------------------------------
// prep_all (512 thr) — single fused launch. NT hints (via ext_vector f32x4:
// __builtin_nontemporal_* rejects HIP_vector_type): w/x are read-once, qw is
// write-only-never-reread -> nontemporal keeps L2/L3 for wq/xq, which the
// GEMM reads next. Math identical to R13 (outputs bit-exact).
//   blocks [0,4096):  block = weight row m. Dequant -> qw (f32, exact) and
//                     cw[m] = max_t mv[m,t] via in-block reduce; wq i8.
//   blocks [4096,12288): x row quantize -> xq (i8), sx[row] = rowmax/127^2.
// ---------------------------------------------------------------------------
__global__ __launch_bounds__(512) void prep_all(const float* __restrict__ w,
                                                const float* __restrict__ maxval,
                                                const float* __restrict__ lut_g,
                                                float* __restrict__ qw,
                                                signed char* __restrict__ wq,
                                                float* __restrict__ cw,
                                                const float* __restrict__ x,
                                                signed char* __restrict__ xq,
                                                float* __restrict__ sx) {
    __shared__ float wm[8];
    __shared__ float lut[16];
    const int tid = threadIdx.x;

    if (blockIdx.x < 4096) {
        const int m = blockIdx.x;                       // weight row
        if (tid < 16) lut[tid] = lut_g[tid];

        size_t base = ((size_t)m * 512 + tid) * 8;      // = m*4096 + tid*8
        float mv = maxval[base >> 6];                   // = maxval[m*64 + tid/8]

        // in-block cw[m] = max over the row's 64 scale blocks
        float mx = mv;
        #pragma unroll
        for (int off = 1; off < 64; off <<= 1)
            mx = fmaxf(mx, __shfl_xor(mx, off, 64));
        if ((tid & 63) == 0) wm[tid >> 6] = mx;
        __syncthreads();
        float cwm = fmaxf(fmaxf(fmaxf(wm[0], wm[1]), fmaxf(wm[2], wm[3])),
                          fmaxf(fmaxf(wm[4], wm[5]), fmaxf(wm[6], wm[7])));

        f32x4 w0 = __builtin_nontemporal_load(
            reinterpret_cast<const f32x4*>(w + base));
        f32x4 w1 = __builtin_nontemporal_load(
            reinterpret_cast<const f32x4*>(w + base + 4));
        float vin[8] = {w0[0], w0[1], w0[2], w0[3], w1[0], w1[1], w1[2], w1[3]};
        float outv[8];
        int   li[8];

        #pragma unroll
        for (int e = 0; e < 8; ++e) {
            float v = vin[e] / mv;
            float bd = fabsf(v - lut[0]);
            int best = 0;
            #pragma unroll
            for (int k = 1; k < 16; ++k) {
                float d = fabsf(v - lut[k]);
                if (d < bd) { bd = d; best = k; }
            }
            outv[e] = lut[best] * mv;
            li[e]   = best;
        }

        f32x4 o0, o1;
        o0[0] = outv[0]; o0[1] = outv[1]; o0[2] = outv[2]; o0[3] = outv[3];
        o1[0] = outv[4]; o1[1] = outv[5]; o1[2] = outv[6]; o1[3] = outv[7];
        __builtin_nontemporal_store(o0, reinterpret_cast<f32x4*>(qw + base));
        __builtin_nontemporal_store(o1, reinterpret_cast<f32x4*>(qw + base + 4));

        if (wq != nullptr) {
            float s = 127.0f * mv / cwm;
            unsigned u0 = 0, u1 = 0;
            #pragma unroll
            for (int e = 0; e < 4; ++e) {
                int q = (int)rintf(lut[li[e]] * s);
                u0 |= ((unsigned)(q & 255)) << (8 * e);
            }
            #pragma unroll
            for (int e = 0; e < 4; ++e) {
                int q = (int)rintf(lut[li[4 + e]] * s);
                u1 |= ((unsigned)(q & 255)) << (8 * e);
            }
            uint2 pk; pk.x = u0; pk.y = u1;
            *reinterpret_cast<uint2*>(wq + base) = pk;
            if (tid == 0) cw[m] = cwm;
        }
    } else {
        if (xq == nullptr) return;
        const int row = blockIdx.x - 4096;
        const float* xr = x + (size_t)row * K_DIM;

        f32x4 a = __builtin_nontemporal_load(
            reinterpret_cast<const f32x4*>(xr + tid * 8));
        f32x4 b = __builtin_nontemporal_load(
            reinterpret_cast<const f32x4*>(xr + tid * 8 + 4));
        float v[8] = {a[0], a[1], a[2], a[3], b[0], b[1], b[2], b[3]};

        float mx = 0.0f;
        #pragma unroll
        for (int e = 0; e < 8; ++e) mx = fmaxf(mx, fabsf(v[e]));
        #pragma unroll
        for (int off = 1; off < 64; off <<= 1)
            mx = fmaxf(mx, __shfl_xor(mx, off, 64));
        if ((tid & 63) == 0) wm[tid >> 6] = mx;
        __syncthreads();
        float rmax = fmaxf(fmaxf(fmaxf(wm[0], wm[1]), fmaxf(wm[2], wm[3])),
                           fmaxf(fmaxf(wm[4], wm[5]), fmaxf(wm[6], wm[7])));
        float inv = rmax > 0.0f ? 127.0f / rmax : 0.0f;

        unsigned u0 = 0, u1 = 0;
        #pragma unroll
        for (int e = 0; e < 4; ++e) {
            int q = (int)rintf(v[e] * inv);
            q = q > 127 ? 127 : (q < -127 ? -127 : q);
            u0 |= ((unsigned)(q & 255)) << (8 * e);
        }
        #pragma unroll
        for (int e = 0; e < 4; ++e) {
            int q = (int)rintf(v[4 + e] * inv);
            q = q > 127 ? 127 : (q < -127 ? -127 : q);
            u1 |= ((unsigned)(q & 255)) << (8 * e);
        }
        uint2 pk; pk.x = u0; pk.y = u1;
        *reinterpret_cast<uint2*>(xq + (size_t)row * K_DIM + tid * 8) = pk;

        if (tid == 0) sx[row] = rmax / 16129.0f;
    }
}

// ---------------------------------------------------------------------------
// i8 256x256 GEMM, 2 phases per K-tile (R13's exact schedule — best measured
// at 131.5 us steady across 6 structural variants):
//   acci = Σ xq*wq (pure i32 C-operand accumulation); y = acci*sx[t]*cw[m].
// 8 waves (2Mx4N), BK=64, LDS 64KB dbuf (2 blocks/CU); regions 8KB:
//   r0=A(MH0) r1=B(NH1) r2=A(MH1) r3=B(NH0).
// PH_A(t): reads r0,r1,r3 (8 ds_reads); stage r2 of t+1 (1 copy);
//          barrier; MFMA quads (0,0)+(0,1) (16).
// PH_B(t): reads r2 (4 ds_reads); stage r0,r1,r3 of t+2 (3 copies);
//          vmcnt(3) BEFORE barrier -> retires B(t-1)'s 3 + A(t)'s 1 =
//          all of tile t+1, certified for PH_A(t+1)'s reads;
//          barrier; MFMA quads (1,1)+(1,0) (16).
// Overwrite safety: staged region's last read is exactly one barrier back.
// Fragment mfma_i32_16x16x64_i8: lane k0=(lane>>4)*16 [HW-verified R9/R11].
// LDS swizzle slot=q^((row>>1)&3) [HW-verified: 0 conflicts].
// Schedule-lever ledger: 4-phase=150us (R11), 2-phase=131.5 (R13),
// 3-buf 1-phase=137 (R14), pipelined reads=136 (R15), +SGB=137 (R17).
// ---------------------------------------------------------------------------

#define RD_A8(BUF, MH)                                                        \
  { _Pragma("unroll") for (int mi = 0; mi < 4; ++mi) {                        \
        int r_ = wr * 64 + mi * 16 + fr;                                      \
        aI[mi] = *reinterpret_cast<const i32x4*>(                             \
            lds + (BUF) * 32768 + (MH) * 16384 + r_ * 64 +                    \
            (fkB ^ (((r_ >> 1) & 3) << 4)));                                  \
  } }

#define RD_B8(BUF, NH, DST)                                                   \
  { _Pragma("unroll") for (int ni = 0; ni < 2; ++ni) {                        \
        int r_ = wc * 32 + ni * 16 + fr;                                      \
        DST[ni] = *reinterpret_cast<const i32x4*>(                            \
            lds + (BUF) * 32768 + ((NH) ? 8192 : 24576) + r_ * 64 +           \
            (fkB ^ (((r_ >> 1) & 3) << 4)));                                  \
  } }

#define MFMA_Q(MH, NH, B)                                                     \
    _Pragma("unroll") for (int mi = 0; mi < 4; ++mi)                          \
    _Pragma("unroll") for (int ni = 0; ni < 2; ++ni)                          \
        acci[(MH) * 4 + mi][(NH) * 2 + ni] =                                  \
            __builtin_amdgcn_mfma_i32_16x16x64_i8(                            \
                aI[mi], B[ni],                                                \
                acci[(MH) * 4 + mi][(NH) * 2 + ni], 0, 0, 0);

#define PH_A(BUF, TNXT)                                                       \
  { RD_A8(BUF, 0)                                                             \
    RD_B8(BUF, 0, bI0)                                                        \
    RD_B8(BUF, 1, bI1)                                                        \
    stage_r2(TNXT);                                                           \
    asm volatile("" ::: "memory");                                            \
    __builtin_amdgcn_s_barrier();                                             \
    asm volatile("" ::: "memory");                                            \
    __builtin_amdgcn_s_setprio(1);                                            \
    MFMA_Q(0, 0, bI0)                                                         \
    MFMA_Q(0, 1, bI1)                                                         \
    __builtin_amdgcn_s_setprio(0); }

#define PH_B(BUF, TNXT2)                                                      \
  { RD_A8(BUF, 1)                                                             \
    stage_r013(TNXT2);                                                        \
    asm volatile("s_waitcnt vmcnt(3)" ::: "memory");                          \
    __builtin_amdgcn_s_barrier();                                             \
    asm volatile("" ::: "memory");                                            \
    __builtin_amdgcn_s_setprio(1);                                            \
    MFMA_Q(1, 1, bI1)                                                         \
    MFMA_Q(1, 0, bI0)                                                         \
    __builtin_amdgcn_s_setprio(0); }

__global__ __launch_bounds__(512, 2) void gemm_i8(
    const signed char* __restrict__ Aq,   // [T][K] int8
    const signed char* __restrict__ Bq,   // [M][K] int8
    const float* __restrict__ sxp,        // [T] rowmax/127^2
    const float* __restrict__ cwp,        // [M] per-column w scale
    float* __restrict__ Y) {
    __shared__ __align__(16) unsigned char lds[65536];

    const int tid  = threadIdx.x;
    const int lane = tid & 63;
    const int wid  = tid >> 6;
    const int wr   = wid >> 2;
    const int wc   = wid & 3;

    const int bid  = blockIdx.x;
    const int swz  = (bid & 7) * 64 + (bid >> 3);   // bijective XCD swizzle
    const int brow = swz >> 4;
    const int bcol = swz & 15;
    const int row0 = brow * 256;
    const int col0 = bcol * 256;

    const int fr  = lane & 15;
    const int fkB = (lane >> 4) * 16;

    i32x4 acci[8][4] = {};
    i32x4 aI[4], bI0[2], bI1[2];

    const int srow  = wid * 16 + (lane >> 2);                 // staging row 0..127
    const int sslot = ((lane & 3) ^ ((srow >> 1) & 3)) * 16;  // pre-swizzled src
    const unsigned sdst = wid * 1024u;                        // linear LDS dest

    auto stage_r013 = [&](int t) {
        int tc  = t < 64 ? t : 63;
        unsigned boff = (unsigned)(t & 1) * 32768u;
        {   // r0: A rows (r%128)<64
            const char* g = (const char*)Aq +
                (size_t)(row0 + ((srow >> 6) << 7) + (srow & 63)) * K_DIM + tc * 64 + sslot;
            async_copy16(g, lds + boff + sdst); }
        {   // r1: B rows (r%64)>=32
            const char* g = (const char*)Bq +
                (size_t)(col0 + ((srow >> 5) << 6) + 32 + (srow & 31)) * K_DIM + tc * 64 + sslot;
            async_copy16(g, lds + boff + 8192u + sdst); }
        {   // r3: B rows (r%64)<32
            const char* g = (const char*)Bq +
                (size_t)(col0 + ((srow >> 5) << 6) + (srow & 31)) * K_DIM + tc * 64 + sslot;
            async_copy16(g, lds + boff + 24576u + sdst); }
    };
    auto stage_r2 = [&](int t) {
        int tc  = t < 64 ? t : 63;
        unsigned boff = (unsigned)(t & 1) * 32768u;
        const char* g = (const char*)Aq +
            (size_t)(row0 + 64 + ((srow >> 6) << 7) + (srow & 63)) * K_DIM + tc * 64 + sslot;
        async_copy16(g, lds + boff + 16384u + sdst);
    };

    // prologue: t0 r0,r1,r3 + t0 r2 + t1 r0,r1,r3 (7 copies);
    // vmcnt(3) retires tile0's 4 -> certified; barrier.
    stage_r013(0);
    stage_r2(0);
    stage_r013(1);
    asm volatile("s_waitcnt vmcnt(3)" ::: "memory");
    __builtin_amdgcn_s_barrier();
    asm volatile("" ::: "memory");

    // main loop: 32 iter x 2 K-tiles x 2 phases
    for (int i = 0; i < 32; ++i) {
        PH_A(0, 2 * i + 1)   // stage r2(t1)
        PH_B(0, 2 * i + 2)   // stage r013(t2); vmcnt(3) certifies tile t1
        PH_A(1, 2 * i + 2)   // stage r2(t2)
        PH_B(1, 2 * i + 3)   // stage r013(t3); vmcnt(3) certifies tile t2
    }
    asm volatile("s_waitcnt vmcnt(0)" ::: "memory");

    // epilogue: C/D col=lane&15, row=(lane>>4)*4+reg; y = acci*sx[t]*cw[m]
    const int rb = (lane >> 4) * 4;
    float cwv[4];
    #pragma unroll
    for (int n = 0; n < 4; ++n) cwv[n] = cwp[col0 + wc * 64 + n * 16 + fr];
    #pragma unroll
    for (int m = 0; m < 8; ++m) {
        const int t0 = row0 + wr * 128 + m * 16 + rb;
        f32x4 sx4 = *reinterpret_cast<const f32x4*>(sxp + t0);
        #pragma unroll
        for (int n = 0; n < 4; ++n)
            #pragma unroll
            for (int r = 0; r < 4; ++r)
                Y[(size_t)(t0 + r) * M_DIM + col0 + wc * 64 + n * 16 + fr] =
                    (float)acci[m][n][r] * sx4[r] * cwv[n];
    }
}

// ---------------------------------------------------------------------------
// Fallback m97-style f32->bf16-in-reg GEMM (only if ws too small)
// ---------------------------------------------------------------------------
__global__ __launch_bounds__(256) void gemm_fb(const float* __restrict__ Ap,
                                               const float* __restrict__ Bp,
                                               float* __restrict__ Y) {
    constexpr int BK = 64;
    __shared__ unsigned short lA[128 * BK];
    __shared__ unsigned short lB[128 * BK];

    const int tid  = threadIdx.x;
    const int lane = tid & 63;
    const int wid  = tid >> 6;
    const int wr   = wid >> 1;
    const int wc   = wid & 1;
    const int brow = blockIdx.x >> 5;
    const int bcol = blockIdx.x & 31;
    const int row0 = brow * 128;
    const int col0 = bcol * 128;

    f32x4 acc[4][4] = {};
    const int fr = lane & 15;
    const int fk = (lane >> 4) * 8;
    const int srow = lane >> 3;
    const int scol = (lane & 7) * 8;

    for (int k0 = 0; k0 < K_DIM; k0 += BK) {
        #pragma unroll
        for (int i = 0; i < 4; ++i) {
            const int c = wid * 4 + i;
            const int r = c * 8 + srow;
            const float* g = Ap + (size_t)(row0 + r) * K_DIM + k0 + scol;
            float4 v0 = *reinterpret_cast<const float4*>(g);
            float4 v1 = *reinterpret_cast<const float4*>(g + 4);
            short8 pk;
            pk[0] = (short)f2b(v0.x); pk[1] = (short)f2b(v0.y);
            pk[2] = (short)f2b(v0.z); pk[3] = (short)f2b(v0.w);
            pk[4] = (short)f2b(v1.x); pk[5] = (short)f2b(v1.y);
            pk[6] = (short)f2b(v1.z); pk[7] = (short)f2b(v1.w);
            *reinterpret_cast<short8*>(lA + c * 512 + lane * 8) = pk;
        }
        #pragma unroll
        for (int i = 0; i < 4; ++i) {
            const int c = wid * 4 + i;
            const int r = c * 8 + srow;
            const float* g = Bp + (size_t)(col0 + r) * K_DIM + k0 + scol;
            float4 v0 = *reinterpret_cast<const float4*>(g);
            float4 v1 = *reinterpret_cast<const float4*>(g + 4);
            short8 pk;
            pk[0] = (short)f2b(v0.x); pk[1] = (short)f2b(v0.y);
            pk[2] = (short)f2b(v0.z); pk[3] = (short)f2b(v0.w);
            pk[4] = (short)f2b(v1.x); pk[5] = (short)f2b(v1.y);
            pk[6] = (short)f2b(v1.z); pk[7] = (short)f2b(v1.w);
            *reinterpret_cast<short8*>(lB + c * 512 + lane * 8) = pk;
        }
        __syncthreads();
        #pragma unroll
        for (int kk = 0; kk < BK; kk += 32) {
            short8 af[4], bfr[4];
            #pragma unroll
            for (int m = 0; m < 4; ++m)
                af[m] = *reinterpret_cast<const short8*>(
                    lA + (wr * 64 + m * 16 + fr) * BK + kk + fk);
            #pragma unroll
            for (int n = 0; n < 4; ++n)
                bfr[n] = *reinterpret_cast<const short8*>(
                    lB + (wc * 64 + n * 16 + fr) * BK + kk + fk);
            #pragma unroll
            for (int m = 0; m < 4; ++m)
                #pragma unroll
                for (int n = 0; n < 4; ++n)
                    acc[m][n] = __builtin_amdgcn_mfma_f32_16x16x32_bf16(
                        af[m], bfr[n], acc[m][n], 0, 0, 0);
        }
        __syncthreads();
    }

    const int orow  = row0 + wr * 64;
    const int ocol  = col0 + wc * 64 + fr;
    const int rbase = (lane >> 4) * 4;
    #pragma unroll
    for (int m = 0; m < 4; ++m)
        #pragma unroll
        for (int n = 0; n < 4; ++n)
            #pragma unroll
            for (int r = 0; r < 4; ++r)
                Y[(size_t)(orow + m * 16 + rbase + r) * M_DIM + ocol + n * 16] =
                    acc[m][n][r];
}

// ---------------------------------------------------------------------------
extern "C" void kernel_launch(void* const* d_in, const int* in_sizes, int n_in,
                              void* d_out, int out_size, void* d_ws, size_t ws_size,
                              hipStream_t stream) {
    const float* x   = (const float*)d_in[0];
    const float* w   = (const float*)d_in[1];
    const float* mv  = (const float*)d_in[2];
    const float* lut = (const float*)d_in[3];

    float* y  = (float*)d_out;
    float* qw = y + (size_t)T_DIM * M_DIM;

    const bool full = ws_size >= (49u << 20);   // need ~48.08 MB

    signed char* xq  = (signed char*)d_ws;                 // 32 MB
    signed char* wqp = xq + (32u << 20);                   // 16 MB
    float*       sx  = (float*)(xq + (48u << 20));         // 32 KB
    float*       cw  = (float*)(xq + (48u << 20) + 65536); // 16 KB

    if (full) {
        prep_all<<<dim3(12288), dim3(512), 0, stream>>>(
            w, mv, lut, qw, wqp, cw, x, xq, sx);
        gemm_i8<<<dim3(512), dim3(512), 0, stream>>>(xq, wqp, sx, cw, y);
    } else {
        prep_all<<<dim3(4096), dim3(512), 0, stream>>>(
            w, mv, lut, qw, nullptr, nullptr, x, nullptr, nullptr);
        dim3 grid((T_DIM / 128) * (M_DIM / 128));
        gemm_fb<<<grid, dim3(256), 0, stream>>>(x, qw, y);
    }
}